// Round 1
// baseline (963.477 us; speedup 1.0000x reference)
//
#include <hip/hip_runtime.h>
#include <math.h>

// Problem constants: B=8, N=1024, C=256, KS=512, H=8, HD=64
// ws layout (float offsets): stats[32] | q[8192*512] | k[8192*512] | Qt[64][64][1024] | Kb[64][1024][64]
#define S_STAT 0
#define S_Q    32
#define S_K    (32 + 4194304)
#define S_QT   (32 + 8388608)
#define S_KB   (32 + 12582912)

__device__ __forceinline__ float wave_sum(float v) {
#pragma unroll
    for (int m = 1; m < 64; m <<= 1) v += __shfl_xor(v, m);
    return v;
}
__device__ __forceinline__ float wave_max(float v) {
#pragma unroll
    for (int m = 1; m < 64; m <<= 1) v = fmaxf(v, __shfl_xor(v, m));
    return v;
}

__global__ __launch_bounds__(64) void k0_zero(float* __restrict__ ws) {
    if (threadIdx.x < 32) ws[S_STAT + threadIdx.x] = 0.0f;
}

// K1: q = x @ qw^T (j-tiles 0..7), k = x @ kw^T (j-tiles 8..15). 64x64 tile per WG.
// Also accumulates per-head sum/sumsq (each WG touches exactly one (tensor,head)).
__global__ __launch_bounds__(256) void k1_gemm(const float* __restrict__ x,
                                               const float* __restrict__ qw,
                                               const float* __restrict__ kw,
                                               float* __restrict__ ws) {
    __shared__ float xa[64][20];
    __shared__ float wb[64][20];
    __shared__ float red[8];
    const int t  = threadIdx.x;
    const int n0 = blockIdx.x * 64;
    const int ty = blockIdx.y;
    const bool is_q = (ty < 8);
    const int j0 = (ty & 7) * 64;
    const float* __restrict__ W = is_q ? qw : kw;
    float* __restrict__ outp = ws + (is_q ? S_Q : S_K);

    const int lr = t >> 2;         // staging row 0..63
    const int lc = (t & 3) * 4;    // staging col {0,4,8,12}
    const int tr = (t >> 4) * 4;   // compute row group
    const int tc = (t & 15) * 4;   // compute col group

    float acc[4][4];
#pragma unroll
    for (int i = 0; i < 4; ++i)
#pragma unroll
        for (int j = 0; j < 4; ++j) acc[i][j] = 0.0f;

    for (int kc = 0; kc < 256; kc += 16) {
        __syncthreads();
        *(float4*)(&xa[lr][lc]) = *(const float4*)(x + (size_t)(n0 + lr) * 256 + kc + lc);
        *(float4*)(&wb[lr][lc]) = *(const float4*)(W + (size_t)(j0 + lr) * 256 + kc + lc);
        __syncthreads();
#pragma unroll
        for (int k4 = 0; k4 < 16; k4 += 4) {
            float4 av[4], bv[4];
#pragma unroll
            for (int i = 0; i < 4; ++i) av[i] = *(const float4*)(&xa[tr + i][k4]);
#pragma unroll
            for (int j = 0; j < 4; ++j) bv[j] = *(const float4*)(&wb[tc + j][k4]);
#pragma unroll
            for (int i = 0; i < 4; ++i)
#pragma unroll
                for (int j = 0; j < 4; ++j)
                    acc[i][j] = fmaf(av[i].x, bv[j].x,
                                fmaf(av[i].y, bv[j].y,
                                fmaf(av[i].z, bv[j].z,
                                fmaf(av[i].w, bv[j].w, acc[i][j]))));
        }
    }
#pragma unroll
    for (int i = 0; i < 4; ++i) {
        float4 o = make_float4(acc[i][0], acc[i][1], acc[i][2], acc[i][3]);
        *(float4*)(outp + (size_t)(n0 + tr + i) * 512 + j0 + tc) = o;
    }
    // per-head stats
    float s1 = 0.0f, s2 = 0.0f;
#pragma unroll
    for (int i = 0; i < 4; ++i)
#pragma unroll
        for (int j = 0; j < 4; ++j) { s1 += acc[i][j]; s2 += acc[i][j] * acc[i][j]; }
    s1 = wave_sum(s1);
    s2 = wave_sum(s2);
    if ((t & 63) == 0) { red[t >> 6] = s1; red[4 + (t >> 6)] = s2; }
    __syncthreads();
    if (t == 0) {
        float t1 = red[0] + red[1] + red[2] + red[3];
        float t2 = red[4] + red[5] + red[6] + red[7];
        const int base = (is_q ? 0 : 16) + (ty & 7);
        atomicAdd(ws + S_STAT + base, t1);
        atomicAdd(ws + S_STAT + base + 8, t2);
    }
}

// K3: BN(train) + L2-normalize per 64-vector.
// z=0: Q -> Qt[bh][d][n] (transposed via LDS).  z=1: K*(1/16) -> Kb[bh][n][d].
__global__ __launch_bounds__(256) void k3_norm(const float* __restrict__ bnw,
                                               const float* __restrict__ bnb,
                                               float* __restrict__ ws) {
    __shared__ float tile[64][65];
    const int t = threadIdx.x;
    const int w = t >> 6, l = t & 63;
    const int nb = blockIdx.x;
    const int bh = blockIdx.y;
    const int b = bh >> 3, h = bh & 7;
    const int z = blockIdx.z;
    const float* __restrict__ in = ws + (z ? S_K : S_Q);
    const float* st = ws + S_STAT + (z ? 16 : 0);
    const float inv_m = 1.0f / 524288.0f;
    const float mean  = st[h] * inv_m;
    const float var   = st[8 + h] * inv_m - mean * mean;
    const float alpha = rsqrtf(var + 1e-5f) * bnw[h];
    const float beta  = bnb[h] - mean * alpha;

    if (z == 0) {
#pragma unroll 1
        for (int i = 0; i < 16; ++i) {
            const int r = w * 16 + i;
            const int n = nb * 64 + r;
            float v = in[(size_t)(b * 1024 + n) * 512 + h * 64 + l];
            v = fmaf(v, alpha, beta);
            float ss = wave_sum(v * v);
            v /= fmaxf(sqrtf(ss), 1e-12f);
            tile[l][r] = v;
        }
        __syncthreads();
        float* qt = ws + S_QT + (size_t)bh * 65536;
        const int d = t >> 2;
#pragma unroll
        for (int i = 0; i < 4; ++i) {
            const int j = (t & 3) * 4 + i * 16;
            float4 o = make_float4(tile[d][j], tile[d][j + 1], tile[d][j + 2], tile[d][j + 3]);
            *(float4*)(qt + d * 1024 + nb * 64 + j) = o;
        }
    } else {
        float* kb = ws + S_KB;
#pragma unroll 1
        for (int i = 0; i < 16; ++i) {
            const int r = w * 16 + i;
            const int n = nb * 64 + r;
            float v = in[(size_t)(b * 1024 + n) * 512 + h * 64 + l];
            v = fmaf(v, alpha, beta);
            float ss = wave_sum(v * v);
            v = v / fmaxf(sqrtf(ss), 1e-12f) * 0.0625f;   // fold 1/sqrt(256)
            kb[(size_t)(bh * 1024 + n) * 64 + l] = v;
        }
    }
}

// K4: per (bh, 16-column tile): S-tile [1024 x 16] in registers, column sparsemax
// (bisection + exact recompute), transpose through LDS, coalesced output write.
__global__ __launch_bounds__(256) void k4_attn(const float* __restrict__ ws,
                                               float* __restrict__ out) {
    __shared__ union UU {
        struct { float q[8][1024]; float kk[16][64]; } s;   // 36864 B
        float sb[512 * 17];                                 // 34816 B (half-tile transpose)
    } u;
    const int t = threadIdx.x;
    const int w = t >> 6, l = t & 63;
    const int mt = blockIdx.x;       // 0..63 column tiles of 16
    const int bh = blockIdx.y;       // 0..63
    const int b = bh >> 3, h = bh & 7;
    const float* __restrict__ qt = ws + S_QT + (size_t)bh * 65536;
    const float* __restrict__ kb = ws + S_KB + (size_t)(bh * 1024 + mt * 16) * 64;

    // stage K tile [16 cols][64 d] (contiguous 1024 floats)
    *(float4*)((float*)u.s.kk + t * 4) = *(const float4*)(kb + t * 4);

    float acc[16][4];
#pragma unroll
    for (int j = 0; j < 16; ++j)
#pragma unroll
        for (int c = 0; c < 4; ++c) acc[j][c] = 0.0f;

    for (int dc = 0; dc < 64; dc += 8) {
        __syncthreads();
        const float* src = qt + dc * 1024;   // Qt is d-major: straight memcpy to LDS
#pragma unroll
        for (int i = 0; i < 8; ++i) {
            const int off = (i * 256 + t) * 4;
            *(float4*)((float*)u.s.q + off) = *(const float4*)(src + off);
        }
        __syncthreads();
#pragma unroll
        for (int dd = 0; dd < 8; ++dd) {
            const float kv0 = u.s.kk[w * 4 + 0][dc + dd];
            const float kv1 = u.s.kk[w * 4 + 1][dc + dd];
            const float kv2 = u.s.kk[w * 4 + 2][dc + dd];
            const float kv3 = u.s.kk[w * 4 + 3][dc + dd];
#pragma unroll
            for (int j = 0; j < 16; ++j) {
                const float qv = u.s.q[dd][j * 64 + l];
                acc[j][0] = fmaf(qv, kv0, acc[j][0]);
                acc[j][1] = fmaf(qv, kv1, acc[j][1]);
                acc[j][2] = fmaf(qv, kv2, acc[j][2]);
                acc[j][3] = fmaf(qv, kv3, acc[j][3]);
            }
        }
    }

    // --- sparsemax per column (wave w owns columns w*4..w*4+3; lane l holds rows l+64j) ---
    float tau[4];
#pragma unroll
    for (int cc = 0; cc < 4; ++cc) {
        float z[16];
#pragma unroll
        for (int j = 0; j < 16; ++j) z[j] = acc[j][cc];
        float vmax = z[0], vsum = z[0];
#pragma unroll
        for (int j = 1; j < 16; ++j) { vmax = fmaxf(vmax, z[j]); vsum += z[j]; }
        vmax = wave_max(vmax);
        vsum = wave_sum(vsum);
        // tau* in [lo, hi]: lo <= tau* always; f(hi) <= 0 always.
        float lo = fmaxf(vmax - 1.0f, (vsum - 1.0f) * (1.0f / 1024.0f));
        float hi = vmax - (1.0f / 1024.0f);
#pragma unroll 1
        for (int it = 0; it < 12; ++it) {
            const float mid = 0.5f * (lo + hi);
            float s = 0.0f;
#pragma unroll
            for (int j = 0; j < 16; ++j) s += fmaxf(z[j] - mid, 0.0f);
            s = wave_sum(s);
            if (s > 1.0f) lo = mid; else hi = mid;   // s uniform -> no divergence
        }
        // exact recompute on the (near-)support set; ties at tau don't shift tau.
        float cnt = 0.0f, ssum = 0.0f;
#pragma unroll
        for (int j = 0; j < 16; ++j) {
            if (z[j] > lo) { cnt += 1.0f; ssum += z[j]; }
        }
        cnt = wave_sum(cnt);
        ssum = wave_sum(ssum);
        tau[cc] = (ssum - 1.0f) / cnt;
    }

    // --- transpose through LDS in two 512-row halves, coalesced store ---
    const int c4 = (t & 3) * 4;
    const int rr = t >> 2;
    float* __restrict__ ob = out + (size_t)b * 1024 * 8192 + h * 1024 + mt * 16 + c4;
#pragma unroll 1
    for (int half = 0; half < 2; ++half) {
        __syncthreads();   // LDS (q/kk or previous half) no longer needed
#pragma unroll
        for (int cc = 0; cc < 4; ++cc) {
            const int c = w * 4 + cc;
#pragma unroll
            for (int j = 0; j < 8; ++j) {
                u.sb[(j * 64 + l) * 17 + c] = fmaxf(acc[half * 8 + j][cc] - tau[cc], 0.0f);
            }
        }
        __syncthreads();
#pragma unroll 1
        for (int it = 0; it < 8; ++it) {
            const int rloc = it * 64 + rr;               // 0..511
            const int n = half * 512 + rloc;
            const float* sp = &u.sb[rloc * 17 + c4];
            float4 o = make_float4(sp[0], sp[1], sp[2], sp[3]);
            *(float4*)(ob + (size_t)n * 8192) = o;
        }
    }
}

extern "C" void kernel_launch(void* const* d_in, const int* in_sizes, int n_in,
                              void* d_out, int out_size, void* d_ws, size_t ws_size,
                              hipStream_t stream) {
    (void)in_sizes; (void)n_in; (void)out_size; (void)ws_size;
    const float* x   = (const float*)d_in[0];
    const float* qw  = (const float*)d_in[1];
    const float* kw  = (const float*)d_in[2];
    const float* bnw = (const float*)d_in[3];
    const float* bnb = (const float*)d_in[4];
    float* ws  = (float*)d_ws;
    float* out = (float*)d_out;

    hipLaunchKernelGGL(k0_zero, dim3(1), dim3(64), 0, stream, ws);
    hipLaunchKernelGGL(k1_gemm, dim3(128, 16), dim3(256), 0, stream, x, qw, kw, ws);
    hipLaunchKernelGGL(k3_norm, dim3(16, 64, 2), dim3(256), 0, stream, bnw, bnb, ws);
    hipLaunchKernelGGL(k4_attn, dim3(64, 64), dim3(256), 0, stream, ws, out);
}